// Round 2
// baseline (143.675 us; speedup 1.0000x reference)
//
#include <hip/hip_runtime.h>
#include <stdint.h>

#define N_BOX 1024
#define NUM_CLASSES 80
#define MAX_OUT 100
#define MASK_WORDS (N_BOX / 64)  // 16 u64 words per row

// Kernel A: pairwise IoU > 0.5 bitmask over original box indices (shared by all classes).
// Grid: 64 blocks x 256 threads, 16 rows per block. One wave -> one u64 word via ballot.
__global__ __launch_bounds__(256) void iou_mask_kernel(const float* __restrict__ boxes,
                                                       unsigned long long* __restrict__ M) {
    __shared__ float4 sbox[N_BOX];   // 16 KB
    __shared__ float  sarea[N_BOX];  // 4 KB
    const int tid = threadIdx.x;
    for (int i = tid; i < N_BOX; i += 256) {
        float4 b = reinterpret_cast<const float4*>(boxes)[i];  // [y1,x1,y2,x2]
        sbox[i] = b;
        sarea[i] = (b.z - b.x) * (b.w - b.y);
    }
    __syncthreads();
    const int lane = tid & 63;
    const int wave = tid >> 6;
    const int row0 = blockIdx.x * 16;
    for (int r = 0; r < 16; ++r) {
        int row = row0 + r;
        float4 br = sbox[row];
        float ar = sarea[row];
#pragma unroll
        for (int k = 0; k < N_BOX / 256; ++k) {
            int col = k * 256 + wave * 64 + lane;
            float4 bc = sbox[col];
            // Match numpy op-for-op: min/max, clip at 0, inter/(ai+aj-inter), real divide.
            float ih = fminf(br.z, bc.z) - fmaxf(br.x, bc.x);
            ih = fmaxf(ih, 0.0f);
            float iw = fminf(br.w, bc.w) - fmaxf(br.y, bc.y);
            iw = fmaxf(iw, 0.0f);
            float inter = ih * iw;
            float uni = ar + sarea[col] - inter;
            unsigned long long m = __ballot((inter / uni) > 0.5f);
            if (lane == 0) M[(size_t)row * MASK_WORDS + k * 4 + wave] = m;
        }
    }
}

// Kernel B: one block per class. Bitonic-sort 64-bit keys (score_bits<<32 | (0xFFFFFFFF-idx))
// descending (=> descending score, ties by ascending index, matching stable argsort of -scores).
// Then wave-0 greedy NMS using the precomputed bitmask, suppressed-mask register-distributed.
__global__ __launch_bounds__(256) void nms_class_kernel(const float* __restrict__ scores,
                                                        const unsigned long long* __restrict__ M,
                                                        int* __restrict__ keptIdx,
                                                        int* __restrict__ counts) {
    __shared__ unsigned long long keys[N_BOX];  // 8 KB
    const int c = blockIdx.x;
    const int tid = threadIdx.x;
    const float* sc = scores + (size_t)c * N_BOX;
    for (int i = tid; i < N_BOX; i += 256) {
        unsigned int bits = __float_as_uint(sc[i]);  // scores in [0,1): bit pattern order-preserving
        keys[i] = ((unsigned long long)bits << 32) |
                  (unsigned long long)(0xFFFFFFFFu - (unsigned int)i);
    }
    __syncthreads();
    // Bitonic sort, descending.
    for (int k = 2; k <= N_BOX; k <<= 1) {
        for (int j = k >> 1; j > 0; j >>= 1) {
#pragma unroll
            for (int t = 0; t < N_BOX / 256; ++t) {
                int i = tid + t * 256;
                int ixj = i ^ j;
                if (ixj > i) {
                    unsigned long long a = keys[i];
                    unsigned long long b = keys[ixj];
                    bool descRegion = ((i & k) == 0);
                    bool doSwap = descRegion ? (a < b) : (a > b);
                    if (doSwap) { keys[i] = b; keys[ixj] = a; }
                }
            }
            __syncthreads();
        }
    }
    // Greedy NMS on wave 0. Lanes 0..15 hold the 16 suppressed-mask words in registers.
    if (tid < 64) {
        const int lane = tid;
        unsigned long long supw = 0ull;
        int kept = 0;
        int* outc = keptIdx + c * MAX_OUT;
        bool done = false;
        for (int base = 0; base < N_BOX && !done; base += 64) {
            unsigned long long mykey = keys[base + lane];
            for (int l = 0; l < 64; ++l) {
                unsigned long long kk = __shfl(mykey, l);   // uniform broadcast
                unsigned int khi = (unsigned int)(kk >> 32);
                if (khi <= 0x3F000000u) { done = true; break; }  // score <= 0.5f -> all rest too
                int orig = (int)(0xFFFFFFFFu - (unsigned int)kk);
                bool mybit = (lane == (orig >> 6)) && ((supw >> (orig & 63)) & 1ull);
                if (__ballot(mybit) != 0ull) continue;           // suppressed by a kept box
                if (lane == 0) outc[kept] = orig;
                ++kept;
                if (kept >= MAX_OUT) { done = true; break; }     // ranks >= 100 are dropped anyway
                if (lane < MASK_WORDS) supw |= M[(size_t)orig * MASK_WORDS + lane];
            }
        }
        if (lane == 0) counts[c] = kept;
    }
}

// Kernel C: exclusive prefix over counts, scatter (0, c, idx) rows packed in (c, rank) order.
__global__ __launch_bounds__(256) void compact_kernel(const int* __restrict__ keptIdx,
                                                      const int* __restrict__ counts,
                                                      int* __restrict__ out) {
    __shared__ int offs[NUM_CLASSES + 1];
    if (threadIdx.x == 0) {
        int s = 0;
        for (int c = 0; c < NUM_CLASSES; ++c) { offs[c] = s; s += counts[c]; }
        offs[NUM_CLASSES] = s;
    }
    __syncthreads();
    for (int idx = threadIdx.x; idx < NUM_CLASSES * MAX_OUT; idx += 256) {
        int c = idx / MAX_OUT;
        int r = idx - c * MAX_OUT;
        int o0 = offs[c];
        if (r < offs[c + 1] - o0) {
            int o = o0 + r;
            out[o * 3 + 0] = 0;  // B == 1
            out[o * 3 + 1] = c;
            out[o * 3 + 2] = keptIdx[c * MAX_OUT + r];
        }
    }
}

extern "C" void kernel_launch(void* const* d_in, const int* in_sizes, int n_in,
                              void* d_out, int out_size, void* d_ws, size_t ws_size,
                              hipStream_t stream) {
    const float* boxes = (const float*)d_in[0];   // (1, 1024, 4) f32
    const float* scores = (const float*)d_in[1];  // (1, 80, 1024) f32
    int* out = (int*)d_out;                        // (8000, 3) int32

    unsigned long long* M = (unsigned long long*)d_ws;              // 128 KB
    int* keptIdx = (int*)((char*)d_ws + (size_t)N_BOX * MASK_WORDS * 8);  // 80*100 ints
    int* counts = keptIdx + NUM_CLASSES * MAX_OUT;                  // 80 ints

    iou_mask_kernel<<<64, 256, 0, stream>>>(boxes, M);
    nms_class_kernel<<<NUM_CLASSES, 256, 0, stream>>>(scores, M, keptIdx, counts);
    hipMemsetAsync(d_out, 0, (size_t)out_size * sizeof(int), stream);
    compact_kernel<<<1, 256, 0, stream>>>(keptIdx, counts, out);
}

// Round 3
// 138.112 us; speedup vs baseline: 1.0403x; 1.0403x over previous
//
#include <hip/hip_runtime.h>
#include <stdint.h>

#define N_BOX 1024
#define NUM_CLASSES 80
#define MAX_OUT 100
#define MASK_WORDS (N_BOX / 64)  // 16 u64 words per row

// Kernel A: pairwise IoU > 0.5 bitmask over original box indices (shared by all classes).
// Grid: 64 blocks x 256 threads, 16 rows per block. One wave -> one u64 word via ballot.
__global__ __launch_bounds__(256) void iou_mask_kernel(const float* __restrict__ boxes,
                                                       unsigned long long* __restrict__ M) {
    __shared__ float4 sbox[N_BOX];   // 16 KB
    __shared__ float  sarea[N_BOX];  // 4 KB
    const int tid = threadIdx.x;
    for (int i = tid; i < N_BOX; i += 256) {
        float4 b = reinterpret_cast<const float4*>(boxes)[i];  // [y1,x1,y2,x2]
        sbox[i] = b;
        sarea[i] = (b.z - b.x) * (b.w - b.y);
    }
    __syncthreads();
    const int lane = tid & 63;
    const int wave = tid >> 6;
    const int row0 = blockIdx.x * 16;
    for (int r = 0; r < 16; ++r) {
        int row = row0 + r;
        float4 br = sbox[row];
        float ar = sarea[row];
#pragma unroll
        for (int k = 0; k < N_BOX / 256; ++k) {
            int col = k * 256 + wave * 64 + lane;
            float4 bc = sbox[col];
            // Match numpy op-for-op: min/max, clip at 0, inter/(ai+aj-inter), real divide.
            float ih = fminf(br.z, bc.z) - fmaxf(br.x, bc.x);
            ih = fmaxf(ih, 0.0f);
            float iw = fminf(br.w, bc.w) - fmaxf(br.y, bc.y);
            iw = fmaxf(iw, 0.0f);
            float inter = ih * iw;
            float uni = ar + sarea[col] - inter;
            unsigned long long m = __ballot((inter / uni) > 0.5f);
            if (lane == 0) M[(size_t)row * MASK_WORDS + k * 4 + wave] = m;
        }
    }
}

// Kernel B: one block per class. Bitonic-sort 64-bit keys (score_bits<<32 | (0xFFFFFFFF-idx))
// descending (=> descending score, ties by ascending index, matching stable argsort of -scores).
// Greedy NMS on wave 0 with windowed ballot elimination:
//  - suppression mask S over ORIGINAL indices, distributed: lane w (w<16) holds u64 word w
//  - per 64-window: one u64 shfl to test each lane's candidate against S
//  - per kept box: v_readlane broadcast + one 128B-line global row read + one ballot
//    eliminates every candidate it suppresses (incl. itself: self-IoU = 1 > 0.5)
__global__ __launch_bounds__(256) void nms_class_kernel(const float* __restrict__ scores,
                                                        const unsigned long long* __restrict__ M,
                                                        int* __restrict__ keptIdx,
                                                        int* __restrict__ counts) {
    __shared__ unsigned long long keys[N_BOX];  // 8 KB
    const int c = blockIdx.x;
    const int tid = threadIdx.x;
    const float* sc = scores + (size_t)c * N_BOX;
    for (int i = tid; i < N_BOX; i += 256) {
        unsigned int bits = __float_as_uint(sc[i]);  // scores in [0,1): bit pattern order-preserving
        keys[i] = ((unsigned long long)bits << 32) |
                  (unsigned long long)(0xFFFFFFFFu - (unsigned int)i);
    }
    __syncthreads();
    // Bitonic sort, descending.
    for (int k = 2; k <= N_BOX; k <<= 1) {
        for (int j = k >> 1; j > 0; j >>= 1) {
#pragma unroll
            for (int t = 0; t < N_BOX / 256; ++t) {
                int i = tid + t * 256;
                int ixj = i ^ j;
                if (ixj > i) {
                    unsigned long long a = keys[i];
                    unsigned long long b = keys[ixj];
                    bool descRegion = ((i & k) == 0);
                    bool doSwap = descRegion ? (a < b) : (a > b);
                    if (doSwap) { keys[i] = b; keys[ixj] = a; }
                }
            }
            __syncthreads();
        }
    }
    // Greedy NMS on wave 0 only (waves 1-3 exit; no barriers below).
    if (tid < 64) {
        const int lane = tid;
        unsigned long long S = 0ull;  // lane w<16 holds suppression word w (orig index space)
        int kept = 0;
        int* outc = keptIdx + c * MAX_OUT;
        for (int base = 0; base < N_BOX && kept < MAX_OUT; base += 64) {
            unsigned long long k = keys[base + lane];
            unsigned int hi = (unsigned int)(k >> 32);
            unsigned int o = 0xFFFFFFFFu - (unsigned int)k;  // orig index of my candidate
            bool valid = hi > 0x3F000000u;                   // score > 0.5f (nonneg floats)
            if (__ballot(valid) == 0ull) break;              // sorted: nothing left anywhere
            unsigned int w = o >> 6;
            unsigned long long bit = 1ull << (o & 63);
            unsigned long long Sw = __shfl(S, (int)w);       // word covering my candidate
            bool alive = valid && ((Sw & bit) == 0ull);
            unsigned long long m = __ballot(alive);
            while (m != 0ull && kept < MAX_OUT) {
                int f = __builtin_ctzll(m);                            // first kept in window
                unsigned int of = __builtin_amdgcn_readlane(o, f);     // sgpr broadcast
                const unsigned long long* rowp = M + (size_t)of * MASK_WORDS;
                unsigned long long row_w = rowp[w];            // my candidate's word (1 line)
                unsigned long long row_s = rowp[lane & 15];    // for S update (same line)
                if (lane < MASK_WORDS) S |= row_s;
                if (lane == 0) outc[kept] = (int)of;
                ++kept;
                m &= ~__ballot((row_w & bit) != 0ull);  // drop all f suppresses (incl. f)
            }
        }
        if (lane == 0) counts[c] = kept;
    }
}

// Kernel C: zero output, exclusive prefix over counts, scatter (0, c, idx) packed rows.
__global__ __launch_bounds__(256) void compact_kernel(const int* __restrict__ keptIdx,
                                                      const int* __restrict__ counts,
                                                      int* __restrict__ out) {
    // Zero all 8000*3 = 24000 ints (poisoned 0xAA by harness). 6000 int4 stores.
    int4* o4 = reinterpret_cast<int4*>(out);
    for (int i = threadIdx.x; i < (NUM_CLASSES * MAX_OUT * 3) / 4; i += 256)
        o4[i] = make_int4(0, 0, 0, 0);
    __shared__ int offs[NUM_CLASSES + 1];
    if (threadIdx.x == 0) {
        int s = 0;
        for (int c = 0; c < NUM_CLASSES; ++c) { offs[c] = s; s += counts[c]; }
        offs[NUM_CLASSES] = s;
    }
    __syncthreads();
    for (int idx = threadIdx.x; idx < NUM_CLASSES * MAX_OUT; idx += 256) {
        int c = idx / MAX_OUT;
        int r = idx - c * MAX_OUT;
        int o0 = offs[c];
        if (r < offs[c + 1] - o0) {
            int o = o0 + r;
            out[o * 3 + 0] = 0;  // B == 1
            out[o * 3 + 1] = c;
            out[o * 3 + 2] = keptIdx[c * MAX_OUT + r];
        }
    }
}

extern "C" void kernel_launch(void* const* d_in, const int* in_sizes, int n_in,
                              void* d_out, int out_size, void* d_ws, size_t ws_size,
                              hipStream_t stream) {
    const float* boxes = (const float*)d_in[0];   // (1, 1024, 4) f32
    const float* scores = (const float*)d_in[1];  // (1, 80, 1024) f32
    int* out = (int*)d_out;                        // (8000, 3) int32

    unsigned long long* M = (unsigned long long*)d_ws;                    // 128 KB
    int* keptIdx = (int*)((char*)d_ws + (size_t)N_BOX * MASK_WORDS * 8);  // 80*100 ints
    int* counts = keptIdx + NUM_CLASSES * MAX_OUT;                        // 80 ints

    iou_mask_kernel<<<64, 256, 0, stream>>>(boxes, M);
    nms_class_kernel<<<NUM_CLASSES, 256, 0, stream>>>(scores, M, keptIdx, counts);
    compact_kernel<<<1, 256, 0, stream>>>(keptIdx, counts, out);
}

// Round 4
// 115.712 us; speedup vs baseline: 1.2417x; 1.1936x over previous
//
#include <hip/hip_runtime.h>
#include <stdint.h>

#define N_BOX 1024
#define NUM_CLASSES 80
#define MAX_OUT 100
#define MASK_WORDS (N_BOX / 64)  // 16 u64 words per row

// Kernel A: pairwise IoU > 0.5 bitmask over original box indices (shared by all classes).
__global__ __launch_bounds__(256) void iou_mask_kernel(const float* __restrict__ boxes,
                                                       unsigned long long* __restrict__ M) {
    __shared__ float4 sbox[N_BOX];   // 16 KB
    __shared__ float  sarea[N_BOX];  // 4 KB
    const int tid = threadIdx.x;
    for (int i = tid; i < N_BOX; i += 256) {
        float4 b = reinterpret_cast<const float4*>(boxes)[i];  // [y1,x1,y2,x2]
        sbox[i] = b;
        sarea[i] = (b.z - b.x) * (b.w - b.y);
    }
    __syncthreads();
    const int lane = tid & 63;
    const int wave = tid >> 6;
    const int row0 = blockIdx.x * 16;
    for (int r = 0; r < 16; ++r) {
        int row = row0 + r;
        float4 br = sbox[row];
        float ar = sarea[row];
#pragma unroll
        for (int k = 0; k < N_BOX / 256; ++k) {
            int col = k * 256 + wave * 64 + lane;
            float4 bc = sbox[col];
            // Match numpy op-for-op: min/max, clip at 0, inter/(ai+aj-inter), real divide.
            float ih = fminf(br.z, bc.z) - fmaxf(br.x, bc.x);
            ih = fmaxf(ih, 0.0f);
            float iw = fminf(br.w, bc.w) - fmaxf(br.y, bc.y);
            iw = fmaxf(iw, 0.0f);
            float inter = ih * iw;
            float uni = ar + sarea[col] - inter;
            unsigned long long m = __ballot((inter / uni) > 0.5f);
            if (lane == 0) M[(size_t)row * MASK_WORDS + k * 4 + wave] = m;
        }
    }
}

// Kernel B: one block per class. Bitonic-sort 64-bit keys (score_bits<<32 | (0xFFFFFFFF-idx))
// descending (matching stable argsort of -scores). Greedy NMS on wave 0 with windowed
// ballot elimination; per window, ALL 64 candidate M-rows are bulk-prefetched into LDS
// (one overlapped memory round trip) so the serial per-kept chain runs at LDS latency
// instead of cross-XCD dirty-L2 latency (~1200 cyc -> ~160 cyc per kept box).
__global__ __launch_bounds__(256) void nms_class_kernel(const float* __restrict__ scores,
                                                        const unsigned long long* __restrict__ M,
                                                        int* __restrict__ keptIdx,
                                                        int* __restrict__ counts) {
    __shared__ unsigned long long keys[N_BOX];          // 8 KB
    __shared__ unsigned long long rowbuf[64 * 17];      // 8.5 KB, +1 u64 pad per row
    const int c = blockIdx.x;
    const int tid = threadIdx.x;
    const float* sc = scores + (size_t)c * N_BOX;
    for (int i = tid; i < N_BOX; i += 256) {
        unsigned int bits = __float_as_uint(sc[i]);  // scores in [0,1): bit-order preserving
        keys[i] = ((unsigned long long)bits << 32) |
                  (unsigned long long)(0xFFFFFFFFu - (unsigned int)i);
    }
    __syncthreads();
    // Bitonic sort, descending.
    for (int k = 2; k <= N_BOX; k <<= 1) {
        for (int j = k >> 1; j > 0; j >>= 1) {
#pragma unroll
            for (int t = 0; t < N_BOX / 256; ++t) {
                int i = tid + t * 256;
                int ixj = i ^ j;
                if (ixj > i) {
                    unsigned long long a = keys[i];
                    unsigned long long b = keys[ixj];
                    bool descRegion = ((i & k) == 0);
                    bool doSwap = descRegion ? (a < b) : (a > b);
                    if (doSwap) { keys[i] = b; keys[ixj] = a; }
                }
            }
            __syncthreads();
        }
    }
    // Greedy NMS on wave 0 only (waves 1-3 exit; no barriers below).
    if (tid < 64) {
        const int lane = tid;
        unsigned long long S = 0ull;  // lane w<16 holds suppression word w (orig index space)
        int kept = 0;
        int* outc = keptIdx + c * MAX_OUT;
        for (int base = 0; base < N_BOX && kept < MAX_OUT; base += 64) {
            unsigned long long k = keys[base + lane];
            unsigned int hi = (unsigned int)(k >> 32);
            unsigned int o = 0xFFFFFFFFu - (unsigned int)k;  // orig index of my candidate
            bool valid = hi > 0x3F000000u;                   // score > 0.5f (nonneg floats)
            if (__ballot(valid) == 0ull) break;              // sorted: nothing left anywhere
            // Bulk prefetch: lane's candidate row (128 B) -> rowbuf[lane]. 8x 16B vector
            // loads per lane, all independent -> latency amortized across the window.
            {
                const ulonglong2* gp2 = reinterpret_cast<const ulonglong2*>(M + (size_t)o * MASK_WORDS);
                unsigned long long* lp = &rowbuf[lane * 17];
#pragma unroll
                for (int j = 0; j < MASK_WORDS / 2; ++j) {
                    ulonglong2 v = gp2[j];
                    lp[2 * j] = v.x;
                    lp[2 * j + 1] = v.y;
                }
            }
            unsigned int w = o >> 6;
            unsigned long long bit = 1ull << (o & 63);
            unsigned long long Sw = __shfl(S, (int)w);       // word covering my candidate
            bool alive = valid && ((Sw & bit) == 0ull);
            unsigned long long m = __ballot(alive);
            while (m != 0ull && kept < MAX_OUT) {
                int f = __builtin_ctzll(m);                    // first alive slot in window
                unsigned long long rw = rowbuf[f * 17 + (int)w];        // my candidate's word
                unsigned long long rs = rowbuf[f * 17 + (lane & 15)];   // for S update
                if (lane < MASK_WORDS) S |= rs;
                if (lane == 0) outc[kept] = (int)__builtin_amdgcn_readlane((int)o, f);
                ++kept;
                m &= ~__ballot((rw & bit) != 0ull);  // drop all f suppresses (incl. f itself)
            }
        }
        if (lane == 0) counts[c] = kept;
    }
}

// Kernel C: zero output, exclusive prefix over counts, scatter (0, c, idx) packed rows.
__global__ __launch_bounds__(256) void compact_kernel(const int* __restrict__ keptIdx,
                                                      const int* __restrict__ counts,
                                                      int* __restrict__ out) {
    int4* o4 = reinterpret_cast<int4*>(out);
    for (int i = threadIdx.x; i < (NUM_CLASSES * MAX_OUT * 3) / 4; i += 256)
        o4[i] = make_int4(0, 0, 0, 0);
    __shared__ int offs[NUM_CLASSES + 1];
    if (threadIdx.x == 0) {
        int s = 0;
        for (int c = 0; c < NUM_CLASSES; ++c) { offs[c] = s; s += counts[c]; }
        offs[NUM_CLASSES] = s;
    }
    __syncthreads();
    for (int idx = threadIdx.x; idx < NUM_CLASSES * MAX_OUT; idx += 256) {
        int c = idx / MAX_OUT;
        int r = idx - c * MAX_OUT;
        int o0 = offs[c];
        if (r < offs[c + 1] - o0) {
            int o = o0 + r;
            out[o * 3 + 0] = 0;  // B == 1
            out[o * 3 + 1] = c;
            out[o * 3 + 2] = keptIdx[c * MAX_OUT + r];
        }
    }
}

extern "C" void kernel_launch(void* const* d_in, const int* in_sizes, int n_in,
                              void* d_out, int out_size, void* d_ws, size_t ws_size,
                              hipStream_t stream) {
    const float* boxes = (const float*)d_in[0];   // (1, 1024, 4) f32
    const float* scores = (const float*)d_in[1];  // (1, 80, 1024) f32
    int* out = (int*)d_out;                        // (8000, 3) int32

    unsigned long long* M = (unsigned long long*)d_ws;                    // 128 KB
    int* keptIdx = (int*)((char*)d_ws + (size_t)N_BOX * MASK_WORDS * 8);  // 80*100 ints
    int* counts = keptIdx + NUM_CLASSES * MAX_OUT;                        // 80 ints

    iou_mask_kernel<<<64, 256, 0, stream>>>(boxes, M);
    nms_class_kernel<<<NUM_CLASSES, 256, 0, stream>>>(scores, M, keptIdx, counts);
    compact_kernel<<<1, 256, 0, stream>>>(keptIdx, counts, out);
}